// Round 1
// baseline (1970.609 us; speedup 1.0000x reference)
//
#include <hip/hip_runtime.h>
#include <math.h>

// Problem constants
constexpr int D_MODEL = 1024;
constexpr int N_HEADS = 16;
constexpr int D_HEAD  = 64;       // D_MODEL / N_HEADS
constexpr int SEQ     = 2048;
constexpr int BATCH   = 2;
constexpr int M_ROWS  = BATCH * SEQ;   // 4096
constexpr int QKV_N   = 3 * D_MODEL;   // 3072

// GEMM tiling
#define BM 64
#define BN 64
#define BKK 16

// ---------------------------------------------------------------------------
// Kernel 1: qkv = x @ w_in^T + b_in, scattered into Q/K/V [B,H,S,Dh]
// ---------------------------------------------------------------------------
__global__ __launch_bounds__(256)
void qkv_gemm_kernel(const float* __restrict__ x, const float* __restrict__ w_in,
                     const float* __restrict__ b_in,
                     float* __restrict__ Q, float* __restrict__ K, float* __restrict__ V) {
    __shared__ float As[BKK][BM + 4];   // +4 keeps rows 16B-aligned, ~2-way banks
    __shared__ float Bs[BKK][BN + 4];

    const int tid = threadIdx.x;
    const int n0  = blockIdx.x * BN;
    const int m0  = blockIdx.y * BM;
    const int tx  = tid & 15;
    const int ty  = tid >> 4;
    const int lr  = tid >> 2;          // 0..63 : tile row being loaded
    const int lk  = (tid & 3) * 4;     // 0,4,8,12 : k sub-offset

    float acc[4][4] = {};

    for (int k0 = 0; k0 < D_MODEL; k0 += BKK) {
        const float4 a  = *reinterpret_cast<const float4*>(&x[(m0 + lr) * D_MODEL + k0 + lk]);
        const float4 bb = *reinterpret_cast<const float4*>(&w_in[(n0 + lr) * D_MODEL + k0 + lk]);
        __syncthreads();  // previous iteration's reads done before overwrite
        As[lk + 0][lr] = a.x;  As[lk + 1][lr] = a.y;
        As[lk + 2][lr] = a.z;  As[lk + 3][lr] = a.w;
        Bs[lk + 0][lr] = bb.x; Bs[lk + 1][lr] = bb.y;
        Bs[lk + 2][lr] = bb.z; Bs[lk + 3][lr] = bb.w;
        __syncthreads();

        #pragma unroll
        for (int kk = 0; kk < BKK; ++kk) {
            const float4 av = *reinterpret_cast<const float4*>(&As[kk][ty * 4]);
            const float4 bv = *reinterpret_cast<const float4*>(&Bs[kk][tx * 4]);
            const float aa[4] = {av.x, av.y, av.z, av.w};
            const float bq[4] = {bv.x, bv.y, bv.z, bv.w};
            #pragma unroll
            for (int i = 0; i < 4; ++i)
                #pragma unroll
                for (int j = 0; j < 4; ++j)
                    acc[i][j] += aa[i] * bq[j];
        }
    }

    // Epilogue: add bias, scatter to Q/K/V in [B,H,S,Dh] layout.
    #pragma unroll
    for (int i = 0; i < 4; ++i) {
        const int m = m0 + ty * 4 + i;
        const int b = m >> 11;              // m / 2048
        const int s = m & (SEQ - 1);
        #pragma unroll
        for (int j = 0; j < 4; ++j) {
            const int n  = n0 + tx * 4 + j;
            const float val = acc[i][j] + b_in[n];
            const int t  = n >> 10;         // 0=q,1=k,2=v
            const int jj = n & 1023;
            const int h  = jj >> 6;
            const int d  = jj & 63;
            float* dst = (t == 0) ? Q : (t == 1) ? K : V;
            dst[(((b * N_HEADS + h) * SEQ) + s) * D_HEAD + d] = val;
        }
    }
}

// ---------------------------------------------------------------------------
// Kernel 2: flash attention per (b,h). Block = 16 q-rows x 16 lanes.
// ---------------------------------------------------------------------------
__global__ __launch_bounds__(256)
void attn_kernel(const float* __restrict__ Q, const float* __restrict__ K,
                 const float* __restrict__ V, float* __restrict__ A) {
    __shared__ float Ks[64][65];
    __shared__ float Vs[64][65];
    __shared__ float Ps[16][65];

    const int tid  = threadIdx.x;
    const int bh   = blockIdx.y;              // 0..31
    const int q0   = blockIdx.x * 16;
    const int qr   = tid >> 4;                // 0..15 : my q row in tile
    const int lane = tid & 15;                // 0..15
    const int base = bh * SEQ * D_HEAD;

    // my q row in registers (fully unrolled accesses -> stays in VGPRs)
    float q[64];
    const int qrow = q0 + qr;
    #pragma unroll
    for (int i = 0; i < 16; ++i) {
        const float4 t4 = *reinterpret_cast<const float4*>(&Q[base + qrow * D_HEAD + i * 4]);
        q[4 * i + 0] = t4.x; q[4 * i + 1] = t4.y;
        q[4 * i + 2] = t4.z; q[4 * i + 3] = t4.w;
    }

    float m = -INFINITY, l = 0.0f;
    float acc[4] = {0.f, 0.f, 0.f, 0.f};

    const int lr  = tid >> 2;            // 0..63 : staging row
    const int seg = (tid & 3) * 16;      // 0,16,32,48 : staging d segment

    for (int k0 = 0; k0 < SEQ; k0 += 64) {
        __syncthreads();
        #pragma unroll
        for (int i = 0; i < 4; ++i) {
            const float4 kq = *reinterpret_cast<const float4*>(
                &K[base + (k0 + lr) * D_HEAD + seg + 4 * i]);
            Ks[lr][seg + 4 * i + 0] = kq.x; Ks[lr][seg + 4 * i + 1] = kq.y;
            Ks[lr][seg + 4 * i + 2] = kq.z; Ks[lr][seg + 4 * i + 3] = kq.w;
            const float4 vq = *reinterpret_cast<const float4*>(
                &V[base + (k0 + lr) * D_HEAD + seg + 4 * i]);
            Vs[lr][seg + 4 * i + 0] = vq.x; Vs[lr][seg + 4 * i + 1] = vq.y;
            Vs[lr][seg + 4 * i + 2] = vq.z; Vs[lr][seg + 4 * i + 3] = vq.w;
        }
        __syncthreads();

        // scores: each lane computes 4 key columns (kc = lane + 16j)
        float s[4];
        #pragma unroll
        for (int j = 0; j < 4; ++j) {
            const int kc = lane + 16 * j;
            float sum = 0.0f;
            #pragma unroll
            for (int d = 0; d < 64; ++d) sum += q[d] * Ks[kc][d];
            s[j] = sum * 0.125f;    // 1/sqrt(64)
        }

        // online softmax (replicated state across the row's 16 lanes)
        float tmax = fmaxf(fmaxf(s[0], s[1]), fmaxf(s[2], s[3]));
        #pragma unroll
        for (int off = 1; off < 16; off <<= 1)
            tmax = fmaxf(tmax, __shfl_xor(tmax, off));
        const float mn   = fmaxf(m, tmax);
        const float corr = __expf(m - mn);
        float psum = 0.0f;
        #pragma unroll
        for (int j = 0; j < 4; ++j) {
            s[j] = __expf(s[j] - mn);
            psum += s[j];
            Ps[qr][lane + 16 * j] = s[j];
        }
        #pragma unroll
        for (int off = 1; off < 16; off <<= 1)
            psum += __shfl_xor(psum, off);
        l = l * corr + psum;
        m = mn;
        #pragma unroll
        for (int c = 0; c < 4; ++c) acc[c] *= corr;
        __syncthreads();

        // PV: each lane owns d = lane*4 .. lane*4+3
        #pragma unroll 8
        for (int kc = 0; kc < 64; ++kc) {
            const float p = Ps[qr][kc];
            acc[0] += p * Vs[kc][lane * 4 + 0];
            acc[1] += p * Vs[kc][lane * 4 + 1];
            acc[2] += p * Vs[kc][lane * 4 + 2];
            acc[3] += p * Vs[kc][lane * 4 + 3];
        }
    }

    const float inv = 1.0f / l;
    #pragma unroll
    for (int c = 0; c < 4; ++c)
        A[base + qrow * D_HEAD + lane * 4 + c] = acc[c] * inv;
}

// ---------------------------------------------------------------------------
// Kernel 3: out = A(viewed [4096][1024]) @ w_out^T + b_out
// (the [B,H,S,Dh] flatten IS the reference's head-untransposed reshape)
// ---------------------------------------------------------------------------
__global__ __launch_bounds__(256)
void out_gemm_kernel(const float* __restrict__ A, const float* __restrict__ w_out,
                     const float* __restrict__ b_out, float* __restrict__ out) {
    __shared__ float As[BKK][BM + 4];
    __shared__ float Bs[BKK][BN + 4];

    const int tid = threadIdx.x;
    const int n0  = blockIdx.x * BN;
    const int m0  = blockIdx.y * BM;
    const int tx  = tid & 15;
    const int ty  = tid >> 4;
    const int lr  = tid >> 2;
    const int lk  = (tid & 3) * 4;

    float acc[4][4] = {};

    for (int k0 = 0; k0 < D_MODEL; k0 += BKK) {
        const float4 a  = *reinterpret_cast<const float4*>(&A[(m0 + lr) * D_MODEL + k0 + lk]);
        const float4 bb = *reinterpret_cast<const float4*>(&w_out[(n0 + lr) * D_MODEL + k0 + lk]);
        __syncthreads();
        As[lk + 0][lr] = a.x;  As[lk + 1][lr] = a.y;
        As[lk + 2][lr] = a.z;  As[lk + 3][lr] = a.w;
        Bs[lk + 0][lr] = bb.x; Bs[lk + 1][lr] = bb.y;
        Bs[lk + 2][lr] = bb.z; Bs[lk + 3][lr] = bb.w;
        __syncthreads();

        #pragma unroll
        for (int kk = 0; kk < BKK; ++kk) {
            const float4 av = *reinterpret_cast<const float4*>(&As[kk][ty * 4]);
            const float4 bv = *reinterpret_cast<const float4*>(&Bs[kk][tx * 4]);
            const float aa[4] = {av.x, av.y, av.z, av.w};
            const float bq[4] = {bv.x, bv.y, bv.z, bv.w};
            #pragma unroll
            for (int i = 0; i < 4; ++i)
                #pragma unroll
                for (int j = 0; j < 4; ++j)
                    acc[i][j] += aa[i] * bq[j];
        }
    }

    #pragma unroll
    for (int i = 0; i < 4; ++i) {
        const int m = m0 + ty * 4 + i;
        float4 st;
        st.x = acc[i][0] + b_out[n0 + tx * 4 + 0];
        st.y = acc[i][1] + b_out[n0 + tx * 4 + 1];
        st.z = acc[i][2] + b_out[n0 + tx * 4 + 2];
        st.w = acc[i][3] + b_out[n0 + tx * 4 + 3];
        *reinterpret_cast<float4*>(&out[m * D_MODEL + n0 + tx * 4]) = st;
    }
}

// ---------------------------------------------------------------------------
extern "C" void kernel_launch(void* const* d_in, const int* in_sizes, int n_in,
                              void* d_out, int out_size, void* d_ws, size_t ws_size,
                              hipStream_t stream) {
    const float* x     = (const float*)d_in[0];
    const float* w_in  = (const float*)d_in[1];
    const float* b_in  = (const float*)d_in[2];
    const float* w_out = (const float*)d_in[3];
    const float* b_out = (const float*)d_in[4];
    float* out = (float*)d_out;

    const size_t tensor_elems = (size_t)BATCH * N_HEADS * SEQ * D_HEAD;  // 4.19M
    float* Q = (float*)d_ws;
    float* K = Q + tensor_elems;
    float* V = K + tensor_elems;
    float* A = V + tensor_elems;

    qkv_gemm_kernel<<<dim3(QKV_N / BN, M_ROWS / BM), 256, 0, stream>>>(
        x, w_in, b_in, Q, K, V);
    attn_kernel<<<dim3(SEQ / 16, BATCH * N_HEADS), 256, 0, stream>>>(Q, K, V, A);
    out_gemm_kernel<<<dim3(D_MODEL / BN, M_ROWS / BM), 256, 0, stream>>>(
        A, w_out, b_out, out);
}

// Round 2
// 558.533 us; speedup vs baseline: 3.5282x; 3.5282x over previous
//
#include <hip/hip_runtime.h>
#include <math.h>

// Problem constants
constexpr int D_MODEL = 1024;
constexpr int N_HEADS = 16;
constexpr int D_HEAD  = 64;       // D_MODEL / N_HEADS
constexpr int SEQ     = 2048;
constexpr int BATCH   = 2;
constexpr int M_ROWS  = BATCH * SEQ;   // 4096
constexpr int QKV_N   = 3 * D_MODEL;   // 3072

// GEMM tiling (fp32 GEMMs unchanged this round)
#define BM 64
#define BN 64
#define BKK 16

typedef __bf16 bf16x8 __attribute__((ext_vector_type(8)));
typedef float  f32x4  __attribute__((ext_vector_type(4)));

union U4 { uint4 u; bf16x8 b; ushort s[8]; };

__device__ __forceinline__ unsigned f2bfu(float f) {
    unsigned u = __builtin_bit_cast(unsigned, f);
    return (u + 0x7FFFu + ((u >> 16) & 1u)) >> 16;   // round-to-nearest-even
}

// XOR swizzle: breaks the 128B-row-stride 32-way bank conflict (guide G4/m214)
__device__ __forceinline__ int swz(int row, int bytecol) {
    return row * 128 + (bytecol ^ ((row & 7) << 4));
}

// ---------------------------------------------------------------------------
// Kernel 1: qkv = x @ w_in^T + b_in -> Q/K/V bf16 [B,H,S,Dh]; Q pre-scaled 1/8
// ---------------------------------------------------------------------------
__global__ __launch_bounds__(256)
void qkv_gemm_kernel(const float* __restrict__ x, const float* __restrict__ w_in,
                     const float* __restrict__ b_in,
                     ushort* __restrict__ Q, ushort* __restrict__ K, ushort* __restrict__ V) {
    __shared__ float As[BKK][BM + 4];
    __shared__ float Bs[BKK][BN + 4];

    const int tid = threadIdx.x;
    const int n0  = blockIdx.x * BN;
    const int m0  = blockIdx.y * BM;
    const int tx  = tid & 15;
    const int ty  = tid >> 4;
    const int lr  = tid >> 2;
    const int lk  = (tid & 3) * 4;

    float acc[4][4] = {};

    for (int k0 = 0; k0 < D_MODEL; k0 += BKK) {
        const float4 a  = *reinterpret_cast<const float4*>(&x[(m0 + lr) * D_MODEL + k0 + lk]);
        const float4 bb = *reinterpret_cast<const float4*>(&w_in[(n0 + lr) * D_MODEL + k0 + lk]);
        __syncthreads();
        As[lk + 0][lr] = a.x;  As[lk + 1][lr] = a.y;
        As[lk + 2][lr] = a.z;  As[lk + 3][lr] = a.w;
        Bs[lk + 0][lr] = bb.x; Bs[lk + 1][lr] = bb.y;
        Bs[lk + 2][lr] = bb.z; Bs[lk + 3][lr] = bb.w;
        __syncthreads();

        #pragma unroll
        for (int kk = 0; kk < BKK; ++kk) {
            const float4 av = *reinterpret_cast<const float4*>(&As[kk][ty * 4]);
            const float4 bv = *reinterpret_cast<const float4*>(&Bs[kk][tx * 4]);
            const float aa[4] = {av.x, av.y, av.z, av.w};
            const float bq[4] = {bv.x, bv.y, bv.z, bv.w};
            #pragma unroll
            for (int i = 0; i < 4; ++i)
                #pragma unroll
                for (int j = 0; j < 4; ++j)
                    acc[i][j] += aa[i] * bq[j];
        }
    }

    #pragma unroll
    for (int i = 0; i < 4; ++i) {
        const int m = m0 + ty * 4 + i;
        const int b = m >> 11;
        const int s = m & (SEQ - 1);
        #pragma unroll
        for (int j = 0; j < 4; ++j) {
            const int n  = n0 + tx * 4 + j;
            float val = acc[i][j] + b_in[n];
            const int t  = n >> 10;         // 0=q,1=k,2=v
            const int jj = n & 1023;
            const int h  = jj >> 6;
            const int d  = jj & 63;
            ushort* dst = (t == 0) ? Q : (t == 1) ? K : V;
            if (t == 0) val *= 0.125f;      // fold 1/sqrt(Dh) into Q (exact in bf16)
            dst[(((size_t)(b * N_HEADS + h) * SEQ) + s) * D_HEAD + d] = (ushort)f2bfu(val);
        }
    }
}

// ---------------------------------------------------------------------------
// Kernel 2: bf16 MFMA flash attention.
// Block: 256 thr = 4 waves, 64 q rows (wave w owns q rows w*16..w*16+15).
// Per KV tile (64 keys): S^T = K·Q^T (4 C-tiles x 2 k-chunks = 8 MFMA),
// in-register online softmax (q = lane&15 is lane-local), P redistributed by
// 16 shfl into the B-fragment, O^T += V^T·P (8 MFMA).
// MFMA frag model: A[m][k]: m=l%16, k=(l/16)*8+j ; B[k][n]: n=l%16, same k ;
// C/D: col=l&15, row=(l>>4)*4+reg  (m89-verified).
// ---------------------------------------------------------------------------
__global__ __launch_bounds__(256)
void attn_mfma_kernel(const ushort* __restrict__ Q, const ushort* __restrict__ K,
                      const ushort* __restrict__ V, float* __restrict__ A) {
    __shared__ __align__(16) char Ks[64 * 128];   // [key][d] bf16, swizzled
    __shared__ __align__(16) char Vt[64 * 128];   // [d][key] bf16, swizzled

    const int tid = threadIdx.x;
    const int w   = tid >> 6;          // wave id 0..3
    const int l   = tid & 63;          // lane
    const int h   = l >> 4;            // subgroup 0..3
    const int rl  = l & 15;

    const int bh  = blockIdx.y;
    const int q0  = blockIdx.x * 64;
    const size_t base = (size_t)bh * SEQ * D_HEAD;   // elements

    // Q fragment: lane supplies Q[qrow][c*32 + h*8 + j]
    const int qrow = q0 + w * 16 + rl;
    bf16x8 qf[2];
    {
        const char* qp = (const char*)(Q + base + (size_t)qrow * D_HEAD);
        U4 t0, t1;
        t0.u = *(const uint4*)(qp + h * 16);
        t1.u = *(const uint4*)(qp + 64 + h * 16);
        qf[0] = t0.b; qf[1] = t1.b;
    }

    f32x4 ot[4];                       // O^T acc: ot[dg][r] = O^T[dg*16+h*4+r][q=rl]
    #pragma unroll
    for (int dg = 0; dg < 4; ++dg) ot[dg] = (f32x4){0.f, 0.f, 0.f, 0.f};
    float m_run = -INFINITY, l_run = 0.0f;

    for (int k0 = 0; k0 < SEQ; k0 += 64) {
        __syncthreads();
        // ---- stage K tile [64 keys][64 d], swizzled ----
        {
            const int key = tid >> 2, seg = tid & 3;
            const uint4* src = (const uint4*)(K + base + (size_t)(k0 + key) * D_HEAD);
            uint4 va = src[seg], vb = src[seg + 4];
            *(uint4*)(Ks + swz(key, seg * 16))      = va;
            *(uint4*)(Ks + swz(key, seg * 16 + 64)) = vb;
        }
        // ---- stage V transposed [64 d][64 keys], swizzled ----
        {
            const int kp = (tid & 31) * 2, db = tid >> 5;
            const ushort* r0 = V + base + (size_t)(k0 + kp) * D_HEAD + db * 8;
            U4 a, b;
            a.u = *(const uint4*)r0;
            b.u = *(const uint4*)(r0 + D_HEAD);
            #pragma unroll
            for (int i = 0; i < 8; ++i) {
                const int d = db * 8 + i;
                const unsigned val = (unsigned)a.s[i] | ((unsigned)b.s[i] << 16);
                *(unsigned*)(Vt + (d * 128 + ((kp * 2) ^ ((d & 7) << 4)))) = val;
            }
        }
        __syncthreads();

        // ---- S^T = K_tile · Q^T : lane holds S^T[t*16+h*4+r][q=rl] ----
        f32x4 st[4];
        #pragma unroll
        for (int t = 0; t < 4; ++t) st[t] = (f32x4){0.f, 0.f, 0.f, 0.f};
        #pragma unroll
        for (int c = 0; c < 2; ++c)
            #pragma unroll
            for (int t = 0; t < 4; ++t) {
                const int row = t * 16 + rl;
                const bf16x8 kf = *(const bf16x8*)(Ks + swz(row, c * 64 + h * 16));
                st[t] = __builtin_amdgcn_mfma_f32_16x16x32_bf16(kf, qf[c], st[t], 0, 0, 0);
            }

        // ---- online softmax over this tile's 64 keys (q = rl, lane-local) ----
        float tm = -INFINITY;
        #pragma unroll
        for (int t = 0; t < 4; ++t)
            #pragma unroll
            for (int r = 0; r < 4; ++r) tm = fmaxf(tm, st[t][r]);
        tm = fmaxf(tm, __shfl_xor(tm, 16, 64));
        tm = fmaxf(tm, __shfl_xor(tm, 32, 64));
        const float mnew = fmaxf(m_run, tm);
        const float corr = __expf(m_run - mnew);
        float p[4][4];
        float ps = 0.0f;
        #pragma unroll
        for (int t = 0; t < 4; ++t)
            #pragma unroll
            for (int r = 0; r < 4; ++r) {
                p[t][r] = __expf(st[t][r] - mnew);
                ps += p[t][r];
            }
        ps += __shfl_xor(ps, 16, 64);
        ps += __shfl_xor(ps, 32, 64);
        l_run = l_run * corr + ps;
        m_run = mnew;
        #pragma unroll
        for (int dg = 0; dg < 4; ++dg) ot[dg] *= corr;

        // ---- pack P to bf16 pairs: pk[t][0]=(r0,r1), pk[t][1]=(r2,r3) ----
        unsigned pk[4][2];
        #pragma unroll
        for (int t = 0; t < 4; ++t) {
            pk[t][0] = f2bfu(p[t][0]) | (f2bfu(p[t][1]) << 16);
            pk[t][1] = f2bfu(p[t][2]) | (f2bfu(p[t][3]) << 16);
        }

        // ---- PV: O^T += V^T · P (chunk c = keys c*32..c*32+31) ----
        // B-frag element j: key = c*32 + h*8 + j, q = rl.
        // Source lane: subgroup 2*(h&1) + (j>>2), same rl; register t' = c*2+(h>>1).
        #pragma unroll
        for (int c = 0; c < 2; ++c) {
            const int src0 = ((h & 1) * 2) * 16 + rl;
            // shuffle both t' candidates (shfl reads the SOURCE lane's register,
            // so the register choice must be lane-uniform), select after.
            const unsigned a0 = __shfl(pk[c * 2][0],     src0,      64);
            const unsigned a1 = __shfl(pk[c * 2][1],     src0,      64);
            const unsigned a2 = __shfl(pk[c * 2][0],     src0 + 16, 64);
            const unsigned a3 = __shfl(pk[c * 2][1],     src0 + 16, 64);
            const unsigned b0 = __shfl(pk[c * 2 + 1][0], src0,      64);
            const unsigned b1 = __shfl(pk[c * 2 + 1][1], src0,      64);
            const unsigned b2 = __shfl(pk[c * 2 + 1][0], src0 + 16, 64);
            const unsigned b3 = __shfl(pk[c * 2 + 1][1], src0 + 16, 64);
            const bool hi = (h & 2) != 0;
            U4 pu;
            pu.u.x = hi ? b0 : a0;
            pu.u.y = hi ? b1 : a1;
            pu.u.z = hi ? b2 : a2;
            pu.u.w = hi ? b3 : a3;
            const bf16x8 pf = pu.b;
            #pragma unroll
            for (int dg = 0; dg < 4; ++dg) {
                const int row = dg * 16 + rl;
                const bf16x8 vf = *(const bf16x8*)(Vt + swz(row, c * 64 + h * 16));
                ot[dg] = __builtin_amdgcn_mfma_f32_16x16x32_bf16(vf, pf, ot[dg], 0, 0, 0);
            }
        }
    }

    // ---- epilogue: O = O^T / l, write A[B,H,S,Dh] fp32 ----
    const float inv = 1.0f / l_run;
    #pragma unroll
    for (int dg = 0; dg < 4; ++dg) {
        float4 o;
        o.x = ot[dg][0] * inv; o.y = ot[dg][1] * inv;
        o.z = ot[dg][2] * inv; o.w = ot[dg][3] * inv;
        *(float4*)(A + base + (size_t)qrow * D_HEAD + dg * 16 + h * 4) = o;
    }
}

// ---------------------------------------------------------------------------
// Kernel 3: out = A(viewed [4096][1024]) @ w_out^T + b_out   (fp32, unchanged)
// ---------------------------------------------------------------------------
__global__ __launch_bounds__(256)
void out_gemm_kernel(const float* __restrict__ A, const float* __restrict__ w_out,
                     const float* __restrict__ b_out, float* __restrict__ out) {
    __shared__ float As[BKK][BM + 4];
    __shared__ float Bs[BKK][BN + 4];

    const int tid = threadIdx.x;
    const int n0  = blockIdx.x * BN;
    const int m0  = blockIdx.y * BM;
    const int tx  = tid & 15;
    const int ty  = tid >> 4;
    const int lr  = tid >> 2;
    const int lk  = (tid & 3) * 4;

    float acc[4][4] = {};

    for (int k0 = 0; k0 < D_MODEL; k0 += BKK) {
        const float4 a  = *reinterpret_cast<const float4*>(&A[(m0 + lr) * D_MODEL + k0 + lk]);
        const float4 bb = *reinterpret_cast<const float4*>(&w_out[(n0 + lr) * D_MODEL + k0 + lk]);
        __syncthreads();
        As[lk + 0][lr] = a.x;  As[lk + 1][lr] = a.y;
        As[lk + 2][lr] = a.z;  As[lk + 3][lr] = a.w;
        Bs[lk + 0][lr] = bb.x; Bs[lk + 1][lr] = bb.y;
        Bs[lk + 2][lr] = bb.z; Bs[lk + 3][lr] = bb.w;
        __syncthreads();

        #pragma unroll
        for (int kk = 0; kk < BKK; ++kk) {
            const float4 av = *reinterpret_cast<const float4*>(&As[kk][ty * 4]);
            const float4 bv = *reinterpret_cast<const float4*>(&Bs[kk][tx * 4]);
            const float aa[4] = {av.x, av.y, av.z, av.w};
            const float bq[4] = {bv.x, bv.y, bv.z, bv.w};
            #pragma unroll
            for (int i = 0; i < 4; ++i)
                #pragma unroll
                for (int j = 0; j < 4; ++j)
                    acc[i][j] += aa[i] * bq[j];
        }
    }

    #pragma unroll
    for (int i = 0; i < 4; ++i) {
        const int m = m0 + ty * 4 + i;
        float4 st;
        st.x = acc[i][0] + b_out[n0 + tx * 4 + 0];
        st.y = acc[i][1] + b_out[n0 + tx * 4 + 1];
        st.z = acc[i][2] + b_out[n0 + tx * 4 + 2];
        st.w = acc[i][3] + b_out[n0 + tx * 4 + 3];
        *reinterpret_cast<float4*>(&out[m * D_MODEL + n0 + tx * 4]) = st;
    }
}

// ---------------------------------------------------------------------------
extern "C" void kernel_launch(void* const* d_in, const int* in_sizes, int n_in,
                              void* d_out, int out_size, void* d_ws, size_t ws_size,
                              hipStream_t stream) {
    const float* x     = (const float*)d_in[0];
    const float* w_in  = (const float*)d_in[1];
    const float* b_in  = (const float*)d_in[2];
    const float* w_out = (const float*)d_in[3];
    const float* b_out = (const float*)d_in[4];
    float* out = (float*)d_out;

    const size_t T = (size_t)BATCH * N_HEADS * SEQ * D_HEAD;  // 4.19M elems
    ushort* Qw = (ushort*)d_ws;        // bf16
    ushort* Kw = Qw + T;
    ushort* Vw = Kw + T;
    float*  Aw = (float*)(Vw + T);     // fp32 attention output

    qkv_gemm_kernel<<<dim3(QKV_N / BN, M_ROWS / BM), 256, 0, stream>>>(
        x, w_in, b_in, Qw, Kw, Vw);
    attn_mfma_kernel<<<dim3(SEQ / 64, BATCH * N_HEADS), 256, 0, stream>>>(
        Qw, Kw, Vw, Aw);
    out_gemm_kernel<<<dim3(D_MODEL / BN, M_ROWS / BM), 256, 0, stream>>>(
        Aw, w_out, b_out, out);
}

// Round 3
// 156.852 us; speedup vs baseline: 12.5635x; 3.5609x over previous
//
#include <hip/hip_runtime.h>
#include <math.h>

// Problem constants
constexpr int D_MODEL = 1024;
constexpr int N_HEADS = 16;
constexpr int D_HEAD  = 64;
constexpr int SEQ     = 2048;
constexpr int BATCH   = 2;
constexpr int M_ROWS  = BATCH * SEQ;   // 4096
constexpr int QKV_N   = 3 * D_MODEL;   // 3072
constexpr int KDIM    = 1024;          // K for both GEMMs

typedef __bf16 bf16x8 __attribute__((ext_vector_type(8)));
typedef float  f32x4  __attribute__((ext_vector_type(4)));

union U4 { uint4 u; bf16x8 b; ushort s[8]; };

__device__ __forceinline__ unsigned f2bfu(float f) {
    unsigned u = __builtin_bit_cast(unsigned, f);
    return (u + 0x7FFFu + ((u >> 16) & 1u)) >> 16;   // RNE
}

// XOR swizzle for attn LDS (guide G4/m214)
__device__ __forceinline__ int swz(int row, int bytecol) {
    return row * 128 + (bytecol ^ ((row & 7) << 4));
}

// async global->LDS, 16B per lane (guide Common-mistake #1)
__device__ __forceinline__ void gload16(const void* g, void* l) {
    __builtin_amdgcn_global_load_lds(
        (const __attribute__((address_space(1))) unsigned int*)g,
        (__attribute__((address_space(3))) unsigned int*)l, 16, 0, 0);
}

// ---------------------------------------------------------------------------
// fp32 -> bf16 convert (vectorized, grid-stride). n % 8 == 0.
// ---------------------------------------------------------------------------
__global__ __launch_bounds__(256)
void f32_to_bf16_kernel(const float* __restrict__ in, ushort* __restrict__ out, int n) {
    const int stride = gridDim.x * blockDim.x * 8;
    for (int i = (blockIdx.x * blockDim.x + threadIdx.x) * 8; i < n; i += stride) {
        const float4 a = *reinterpret_cast<const float4*>(in + i);
        const float4 b = *reinterpret_cast<const float4*>(in + i + 4);
        uint4 o;
        o.x = f2bfu(a.x) | (f2bfu(a.y) << 16);
        o.y = f2bfu(a.z) | (f2bfu(a.w) << 16);
        o.z = f2bfu(b.x) | (f2bfu(b.y) << 16);
        o.w = f2bfu(b.z) | (f2bfu(b.w) << 16);
        *reinterpret_cast<uint4*>(out + i) = o;
    }
}

// ---------------------------------------------------------------------------
// Shared MFMA main loop: C[128x128] tile of  A[M][1024] @ B[N][1024]^T,
// m97 structure: BK=32, global_load_lds w16, 2 barriers/K-step,
// 4 waves (2x2), each wave 4x4 frags of 16x16x32.
// ---------------------------------------------------------------------------
__device__ __forceinline__ void mfma_gemm_bt_128(
    const ushort* __restrict__ Ag, const ushort* __restrict__ Bg,
    int m0, int n0, ushort* As, ushort* Bs, f32x4 (&acc)[4][4])
{
    const int tid = threadIdx.x;
    const int l   = tid & 63;
    const int rl  = l & 15, hh = l >> 4;
    const int w   = tid >> 6;
    const int wm  = (w >> 1) * 64, wn = (w & 1) * 64;

    // staging: thread t moves 16B chunks t and t+256 of each 128x32 tile
    const int r0 = tid >> 2;
    const int ce = (tid & 3) * 8;                     // elem offset in row
    const ushort* gA0 = Ag + (size_t)(m0 + r0) * KDIM + ce;
    const ushort* gA1 = gA0 + (size_t)64 * KDIM;
    const ushort* gB0 = Bg + (size_t)(n0 + r0) * KDIM + ce;
    const ushort* gB1 = gB0 + (size_t)64 * KDIM;
    char* lA = (char*)As + tid * 16;
    char* lB = (char*)Bs + tid * 16;

    for (int k0 = 0; k0 < KDIM; k0 += 32) {
        __syncthreads();                               // prior reads done
        gload16(gA0 + k0, lA);
        gload16(gA1 + k0, lA + 4096);
        gload16(gB0 + k0, lB);
        gload16(gB1 + k0, lB + 4096);
        __syncthreads();                               // stage visible

        bf16x8 af[4], bf_[4];
        #pragma unroll
        for (int f = 0; f < 4; ++f)
            af[f]  = *(const bf16x8*)((const char*)As + (wm + f * 16 + rl) * 64 + hh * 16);
        #pragma unroll
        for (int f = 0; f < 4; ++f)
            bf_[f] = *(const bf16x8*)((const char*)Bs + (wn + f * 16 + rl) * 64 + hh * 16);
        #pragma unroll
        for (int i = 0; i < 4; ++i)
            #pragma unroll
            for (int j = 0; j < 4; ++j)
                acc[i][j] = __builtin_amdgcn_mfma_f32_16x16x32_bf16(af[i], bf_[j], acc[i][j], 0, 0, 0);
    }
}

// ---------------------------------------------------------------------------
// Kernel 1: QKV GEMM (bf16 MFMA) -> Q/K/V bf16 [B,H,S,Dh], Q pre-scaled 1/8
// ---------------------------------------------------------------------------
__global__ __launch_bounds__(256)
void qkv_mfma_kernel(const ushort* __restrict__ xb, const ushort* __restrict__ wb,
                     const float* __restrict__ b_in,
                     ushort* __restrict__ Q, ushort* __restrict__ K, ushort* __restrict__ V) {
    __shared__ __align__(16) ushort As[128 * 32];
    __shared__ __align__(16) ushort Bs[128 * 32];

    f32x4 acc[4][4];
    #pragma unroll
    for (int i = 0; i < 4; ++i)
        #pragma unroll
        for (int j = 0; j < 4; ++j) acc[i][j] = (f32x4){0.f, 0.f, 0.f, 0.f};

    const int m0 = blockIdx.y * 128, n0 = blockIdx.x * 128;
    mfma_gemm_bt_128(xb, wb, m0, n0, As, Bs, acc);

    const int l  = threadIdx.x & 63, w = threadIdx.x >> 6;
    const int rl = l & 15, hh = l >> 4;
    const int mb = m0 + (w >> 1) * 64, nb = n0 + (w & 1) * 64;

    #pragma unroll
    for (int j = 0; j < 4; ++j) {
        const int n  = nb + j * 16 + rl;
        const float bias = b_in[n];
        const int t  = n >> 10;            // 0=q,1=k,2=v
        const int jj = n & 1023;
        const int h  = jj >> 6;
        const int d  = jj & 63;
        ushort* dst = (t == 0) ? Q : (t == 1) ? K : V;
        const float sc = (t == 0) ? 0.125f : 1.0f;
        #pragma unroll
        for (int i = 0; i < 4; ++i)
            #pragma unroll
            for (int r = 0; r < 4; ++r) {
                const int m = mb + i * 16 + hh * 4 + r;
                const int b = m >> 11;
                const int s = m & (SEQ - 1);
                dst[((size_t)(b * N_HEADS + h) * SEQ + s) * D_HEAD + d] =
                    (ushort)f2bfu((acc[i][j][r] + bias) * sc);
            }
    }
}

// ---------------------------------------------------------------------------
// Kernel 2: bf16 MFMA flash attention (unchanged core; epilogue now bf16).
// ---------------------------------------------------------------------------
__global__ __launch_bounds__(256)
void attn_mfma_kernel(const ushort* __restrict__ Q, const ushort* __restrict__ K,
                      const ushort* __restrict__ V, ushort* __restrict__ A) {
    __shared__ __align__(16) char Ks[64 * 128];   // [key][d] bf16, swizzled
    __shared__ __align__(16) char Vt[64 * 128];   // [d][key] bf16, swizzled

    const int tid = threadIdx.x;
    const int w   = tid >> 6;
    const int l   = tid & 63;
    const int h   = l >> 4;
    const int rl  = l & 15;

    const int bh  = blockIdx.y;
    const int q0  = blockIdx.x * 64;
    const size_t base = (size_t)bh * SEQ * D_HEAD;

    const int qrow = q0 + w * 16 + rl;
    bf16x8 qf[2];
    {
        const char* qp = (const char*)(Q + base + (size_t)qrow * D_HEAD);
        U4 t0, t1;
        t0.u = *(const uint4*)(qp + h * 16);
        t1.u = *(const uint4*)(qp + 64 + h * 16);
        qf[0] = t0.b; qf[1] = t1.b;
    }

    f32x4 ot[4];
    #pragma unroll
    for (int dg = 0; dg < 4; ++dg) ot[dg] = (f32x4){0.f, 0.f, 0.f, 0.f};
    float m_run = -INFINITY, l_run = 0.0f;

    for (int k0 = 0; k0 < SEQ; k0 += 64) {
        __syncthreads();
        {   // stage K [64 keys][64 d] swizzled
            const int key = tid >> 2, seg = tid & 3;
            const uint4* src = (const uint4*)(K + base + (size_t)(k0 + key) * D_HEAD);
            uint4 va = src[seg], vb = src[seg + 4];
            *(uint4*)(Ks + swz(key, seg * 16))      = va;
            *(uint4*)(Ks + swz(key, seg * 16 + 64)) = vb;
        }
        {   // stage V^T [64 d][64 keys] swizzled
            const int kp = (tid & 31) * 2, db = tid >> 5;
            const ushort* r0 = V + base + (size_t)(k0 + kp) * D_HEAD + db * 8;
            U4 a, b;
            a.u = *(const uint4*)r0;
            b.u = *(const uint4*)(r0 + D_HEAD);
            #pragma unroll
            for (int i = 0; i < 8; ++i) {
                const int d = db * 8 + i;
                const unsigned val = (unsigned)a.s[i] | ((unsigned)b.s[i] << 16);
                *(unsigned*)(Vt + (d * 128 + ((kp * 2) ^ ((d & 7) << 4)))) = val;
            }
        }
        __syncthreads();

        // S^T = K·Q^T
        f32x4 st[4];
        #pragma unroll
        for (int t = 0; t < 4; ++t) st[t] = (f32x4){0.f, 0.f, 0.f, 0.f};
        #pragma unroll
        for (int c = 0; c < 2; ++c)
            #pragma unroll
            for (int t = 0; t < 4; ++t) {
                const int row = t * 16 + rl;
                const bf16x8 kf = *(const bf16x8*)(Ks + swz(row, c * 64 + h * 16));
                st[t] = __builtin_amdgcn_mfma_f32_16x16x32_bf16(kf, qf[c], st[t], 0, 0, 0);
            }

        // online softmax (q = rl lane-local)
        float tm = -INFINITY;
        #pragma unroll
        for (int t = 0; t < 4; ++t)
            #pragma unroll
            for (int r = 0; r < 4; ++r) tm = fmaxf(tm, st[t][r]);
        tm = fmaxf(tm, __shfl_xor(tm, 16, 64));
        tm = fmaxf(tm, __shfl_xor(tm, 32, 64));
        const float mnew = fmaxf(m_run, tm);
        const float corr = __expf(m_run - mnew);
        float p[4][4];
        float ps = 0.0f;
        #pragma unroll
        for (int t = 0; t < 4; ++t)
            #pragma unroll
            for (int r = 0; r < 4; ++r) {
                p[t][r] = __expf(st[t][r] - mnew);
                ps += p[t][r];
            }
        ps += __shfl_xor(ps, 16, 64);
        ps += __shfl_xor(ps, 32, 64);
        l_run = l_run * corr + ps;
        m_run = mnew;
        #pragma unroll
        for (int dg = 0; dg < 4; ++dg) ot[dg] *= corr;

        unsigned pk[4][2];
        #pragma unroll
        for (int t = 0; t < 4; ++t) {
            pk[t][0] = f2bfu(p[t][0]) | (f2bfu(p[t][1]) << 16);
            pk[t][1] = f2bfu(p[t][2]) | (f2bfu(p[t][3]) << 16);
        }

        // O^T += V^T · P
        #pragma unroll
        for (int c = 0; c < 2; ++c) {
            const int src0 = ((h & 1) * 2) * 16 + rl;
            const unsigned a0 = __shfl(pk[c * 2][0],     src0,      64);
            const unsigned a1 = __shfl(pk[c * 2][1],     src0,      64);
            const unsigned a2 = __shfl(pk[c * 2][0],     src0 + 16, 64);
            const unsigned a3 = __shfl(pk[c * 2][1],     src0 + 16, 64);
            const unsigned b0 = __shfl(pk[c * 2 + 1][0], src0,      64);
            const unsigned b1 = __shfl(pk[c * 2 + 1][1], src0,      64);
            const unsigned b2 = __shfl(pk[c * 2 + 1][0], src0 + 16, 64);
            const unsigned b3 = __shfl(pk[c * 2 + 1][1], src0 + 16, 64);
            const bool hi = (h & 2) != 0;
            U4 pu;
            pu.u.x = hi ? b0 : a0;
            pu.u.y = hi ? b1 : a1;
            pu.u.z = hi ? b2 : a2;
            pu.u.w = hi ? b3 : a3;
            const bf16x8 pf = pu.b;
            #pragma unroll
            for (int dg = 0; dg < 4; ++dg) {
                const int row = dg * 16 + rl;
                const bf16x8 vf = *(const bf16x8*)(Vt + swz(row, c * 64 + h * 16));
                ot[dg] = __builtin_amdgcn_mfma_f32_16x16x32_bf16(vf, pf, ot[dg], 0, 0, 0);
            }
        }
    }

    // epilogue: O = O^T / l -> bf16
    const float inv = 1.0f / l_run;
    #pragma unroll
    for (int dg = 0; dg < 4; ++dg) {
        uint2 o;
        o.x = f2bfu(ot[dg][0] * inv) | (f2bfu(ot[dg][1] * inv) << 16);
        o.y = f2bfu(ot[dg][2] * inv) | (f2bfu(ot[dg][3] * inv) << 16);
        *(uint2*)(A + base + (size_t)qrow * D_HEAD + dg * 16 + h * 4) = o;
    }
}

// ---------------------------------------------------------------------------
// Kernel 3: out = A[4096][1024](bf16) @ w_out^T + b_out  (bf16 MFMA, fp32 out)
// ---------------------------------------------------------------------------
__global__ __launch_bounds__(256)
void out_mfma_kernel(const ushort* __restrict__ Ab, const ushort* __restrict__ wb,
                     const float* __restrict__ b_out, float* __restrict__ out) {
    __shared__ __align__(16) ushort As[128 * 32];
    __shared__ __align__(16) ushort Bs[128 * 32];

    f32x4 acc[4][4];
    #pragma unroll
    for (int i = 0; i < 4; ++i)
        #pragma unroll
        for (int j = 0; j < 4; ++j) acc[i][j] = (f32x4){0.f, 0.f, 0.f, 0.f};

    const int m0 = blockIdx.y * 128, n0 = blockIdx.x * 128;
    mfma_gemm_bt_128(Ab, wb, m0, n0, As, Bs, acc);

    const int l  = threadIdx.x & 63, w = threadIdx.x >> 6;
    const int rl = l & 15, hh = l >> 4;
    const int mb = m0 + (w >> 1) * 64, nb = n0 + (w & 1) * 64;

    #pragma unroll
    for (int j = 0; j < 4; ++j) {
        const int n = nb + j * 16 + rl;
        const float bias = b_out[n];
        #pragma unroll
        for (int i = 0; i < 4; ++i)
            #pragma unroll
            for (int r = 0; r < 4; ++r) {
                const int m = mb + i * 16 + hh * 4 + r;
                out[(size_t)m * D_MODEL + n] = acc[i][j][r] + bias;
            }
    }
}

// ---------------------------------------------------------------------------
extern "C" void kernel_launch(void* const* d_in, const int* in_sizes, int n_in,
                              void* d_out, int out_size, void* d_ws, size_t ws_size,
                              hipStream_t stream) {
    const float* x     = (const float*)d_in[0];
    const float* w_in  = (const float*)d_in[1];
    const float* b_in  = (const float*)d_in[2];
    const float* w_out = (const float*)d_in[3];
    const float* b_out = (const float*)d_in[4];
    float* out = (float*)d_out;

    const size_t T = (size_t)BATCH * N_HEADS * SEQ * D_HEAD;  // 4.19M elems
    ushort* Qw  = (ushort*)d_ws;
    ushort* Kw  = Qw + T;
    ushort* Vw  = Kw + T;
    ushort* Aw  = Vw + T;                 // attn out, bf16
    ushort* xb  = Aw + T;                 // x bf16       (4096*1024)
    ushort* wib = xb + (size_t)M_ROWS * D_MODEL;      // w_in bf16  (3072*1024)
    ushort* wob = wib + (size_t)QKV_N * D_MODEL;      // w_out bf16 (1024*1024)

    const int nx = M_ROWS * D_MODEL;      // 4.19M
    const int nwi = QKV_N * D_MODEL;      // 3.15M
    const int nwo = D_MODEL * D_MODEL;    // 1.05M
    f32_to_bf16_kernel<<<2048, 256, 0, stream>>>(x, xb, nx);
    f32_to_bf16_kernel<<<1536, 256, 0, stream>>>(w_in, wib, nwi);
    f32_to_bf16_kernel<<<512, 256, 0, stream>>>(w_out, wob, nwo);

    qkv_mfma_kernel<<<dim3(QKV_N / 128, M_ROWS / 128), 256, 0, stream>>>(
        xb, wib, b_in, Qw, Kw, Vw);
    attn_mfma_kernel<<<dim3(SEQ / 64, BATCH * N_HEADS), 256, 0, stream>>>(
        Qw, Kw, Vw, Aw);
    out_mfma_kernel<<<dim3(D_MODEL / 128, M_ROWS / 128), 256, 0, stream>>>(
        Aw, wob, b_out, out);
}